// Round 20
// baseline (259.434 us; speedup 1.0000x reference)
//
#include <hip/hip_runtime.h>
#include <float.h>

#define DD 768
#define SS 2048
#define BB 4
#define BSR (BB*SS)   // 8192 total rows
#define KNEI 32
#define K2 (3*DD)     // 2304: [hi | x | y] split concat along K (hs_s only)
#define QS (2*DD)     // 1536: 2-slot q_s/k_s layout [h, l*2^6]
#define MARGIN 0.6f   // covers f16 dist storage quant (<=0.25) + f16 gemm err (6sig ~0.11)

typedef __attribute__((ext_vector_type(8))) _Float16 f16x8;
typedef __attribute__((ext_vector_type(4))) float f32x4;
typedef __attribute__((ext_vector_type(8))) unsigned short u16x8;
typedef __attribute__((ext_vector_type(4))) unsigned short u16x4;

__device__ __forceinline__ float f16f(unsigned short u) {
    return (float)__builtin_bit_cast(_Float16, u);
}
__device__ __forceinline__ unsigned short ff16(float x) {
    return __builtin_bit_cast(unsigned short, (_Float16)x);
}
__device__ __forceinline__ unsigned short rne_bf16(float x) {
    unsigned u = __builtin_bit_cast(unsigned, x);
    unsigned r = u + 0x7FFFu + ((u >> 16) & 1u);
    return (unsigned short)(r >> 16);
}
__device__ __forceinline__ float bf16f(unsigned short h) {
    return __builtin_bit_cast(float, (unsigned)h << 16);
}

__device__ __forceinline__ void gload_lds16(const void* g, void* l) {
    __builtin_amdgcn_global_load_lds(
        (const __attribute__((address_space(1))) unsigned int*)g,
        (__attribute__((address_space(3))) unsigned int*)l, 16, 0, 0);
}

// fp32 -> 3-slot f16 split body (8 elems at flat chunk id `idx`).
// A-layout (LO_SLOT=1): [h, l*2^6, h*2^-6];  B-layout (LO_SLOT=2): [h, h*2^-6, l*2^6]
template<int LO_SLOT>
__device__ __forceinline__ void split_body(const float* __restrict__ in,
                                           unsigned short* __restrict__ out,
                                           int idx, int Kc)
{
    int perRow = Kc >> 3;
    int row = idx / perRow, c8 = idx - row * perRow;
    const float* src = in + (long)row * Kc + c8 * 8;
    f32x4 x0 = *(const f32x4*)&src[0];
    f32x4 x1 = *(const f32x4*)&src[4];
    u16x8 hi, lsc, hsc;
    #pragma unroll
    for (int e = 0; e < 8; ++e) {
        float xv = (e < 4) ? x0[e] : x1[e - 4];
        _Float16 h = (_Float16)xv;
        float hf = (float)h;
        float l = xv - hf;
        hi[e]  = __builtin_bit_cast(unsigned short, h);
        lsc[e] = ff16(l * 64.f);
        hsc[e] = ff16(hf * 0.015625f);
    }
    long base = (long)row * (3 * Kc) + c8 * 8;
    *(u16x8*)&out[base] = hi;
    *(u16x8*)&out[base + Kc]     = (LO_SLOT == 1) ? lsc : hsc;
    *(u16x8*)&out[base + 2 * Kc] = (LO_SLOT == 1) ? hsc : lsc;
}

__device__ __forceinline__ void conv_body(const float* __restrict__ in,
                                          unsigned short* __restrict__ out, int idx)
{
    const float* src = in + (long)idx * 8;
    f32x4 x0 = *(const f32x4*)&src[0];
    f32x4 x1 = *(const f32x4*)&src[4];
    u16x8 o;
    #pragma unroll
    for (int e = 0; e < 8; ++e) {
        float xv = (e < 4) ? x0[e] : x1[e - 4];
        o[e] = ff16(xv);
    }
    *(u16x8*)&out[(long)idx * 8] = o;
}

// ---- merged prologue: 3 weight splits + hs split + 2 MLP convs + bias concat ----
__global__ __launch_bounds__(256)
void prep(const float* __restrict__ Wq, const float* __restrict__ Wk,
          const float* __restrict__ Wv, const float* __restrict__ hs,
          const float* __restrict__ W1, const float* __restrict__ W2,
          const float* __restrict__ bq, const float* __restrict__ bk,
          const float* __restrict__ bv,
          unsigned short* __restrict__ Wqkv_s, unsigned short* __restrict__ hs_s,
          unsigned short* __restrict__ W1_f16, unsigned short* __restrict__ W2_f16,
          float* __restrict__ bqkv)
{
    const long WSPL = (long)DD * K2;
    int bid = blockIdx.x;
    int tid = threadIdx.x;
    if (bid < 864) {
        int which = bid / 288, sub = bid - which * 288;
        const float* src = (which == 0) ? Wq : (which == 1) ? Wk : Wv;
        split_body<2>(src, Wqkv_s + (long)which * WSPL, sub * 256 + tid, DD);
    } else if (bid < 3936) {
        split_body<1>(hs, hs_s, (bid - 864) * 256 + tid, DD);
    } else if (bid < 4224) {
        conv_body(W1, W1_f16, (bid - 3936) * 256 + tid);
    } else if (bid < 4512) {
        conv_body(W2, W2_f16, (bid - 4224) * 256 + tid);
    } else {
        int i = (bid - 4512) * 256 + tid;
        if (i < 768) bqkv[i] = bq[i];
        else if (i < 1536) bqkv[i] = bk[i - 768];
        else if (i < 2304) bqkv[i] = bv[i - 1536];
    }
}

// pn rows: qnp[8192][12] then knp[8192][12] contiguous; fixed-order sum.
__global__ __launch_bounds__(256)
void finish_norms(const float* __restrict__ pn, float* __restrict__ qn, float* __restrict__ kn)
{
    int row = blockIdx.x * 256 + threadIdx.x;   // 0..16383
    const float* p = pn + (long)row * 12;
    float s = 0.f;
    #pragma unroll
    for (int c = 0; c < 12; ++c) s += p[c];
    if (row < BSR) qn[row] = s; else kn[row - BSR] = s;
}

// ---------------------------------------------------------------------------
// 256x256-tile distance GEMM, minimum-2-phase __syncthreads schedule.
// Single-term f16 inputs (Kd=768, stride QS); OUTPUT STORED AS F16 (selection
// scratch only — the margin guard re-ranks the boundary from exact splits).
// ---------------------------------------------------------------------------
__global__ __launch_bounds__(512)
void gemm256_dist(const unsigned short* __restrict__ A, const unsigned short* __restrict__ B,
                  const float* __restrict__ rm, const float* __restrict__ rn,
                  unsigned short* __restrict__ C,
                  int N, int Kd, long lda, long ldb,
                  long sA, long sB, long sC, long sR)
{
    const int z = blockIdx.z;
    A += (long)z * sA;
    B += (long)z * sB;
    C += (long)z * sC;
    const float* rmz = rm + (long)z * sR;
    const float* rnz = rn + (long)z * sR;

    // bijective XCD swizzle over the 64 blocks of this batch
    int lid = blockIdx.y * gridDim.x + blockIdx.x;
    int xcd = lid & 7, pos = lid >> 3;
    int nlid = xcd * 8 + pos;
    const int bx = nlid & 7, by = nlid >> 3;

    __shared__ __align__(16) unsigned short lds[2 * 32768];  // 2 bufs x (A 16384 | B 16384) f16

    const int tid = threadIdx.x;
    const int lane = tid & 63;
    const int wave = tid >> 6;
    const int wm = wave >> 2, wn = wave & 3;   // 2 x 4 wave grid
    const int m0 = by * 256, n0 = bx * 256;
    const int r15 = lane & 15;
    const int g4 = lane >> 4;

    f32x4 acc[8][4] = {};

    long aB[4], bB[4];
    int lof[4];
    #pragma unroll
    for (int i = 0; i < 4; ++i) {
        int L = i * 512 + tid;          // 0..2047 chunk id (16B chunks)
        int row = L >> 3, ch = L & 7;
        int chs = ch ^ (row & 7);
        aB[i] = (long)(m0 + row) * lda * 2 + chs * 16;
        bB[i] = (long)(n0 + row) * ldb * 2 + chs * 16;
        lof[i] = L * 8;
    }

    const int NT = Kd >> 6;             // 12 K-tiles of 64

    // prologue: stage tile 0 into buf 0, full drain
    #pragma unroll
    for (int i = 0; i < 4; ++i) {
        gload_lds16((const char*)A + aB[i], &lds[lof[i]]);
        gload_lds16((const char*)B + bB[i], &lds[16384 + lof[i]]);
    }
    __syncthreads();

    int cur = 0;
    for (int t = 0; t < NT; ++t) {
        if (t + 1 < NT) {               // prefetch next tile into the other buffer
            long kb = (long)(t + 1) * 128;
            int off = (cur ^ 1) * 32768;
            #pragma unroll
            for (int i = 0; i < 4; ++i) {
                gload_lds16((const char*)A + aB[i] + kb, &lds[off + lof[i]]);
                gload_lds16((const char*)B + bB[i] + kb, &lds[off + 16384 + lof[i]]);
            }
        }
        const unsigned short* bufA = &lds[cur * 32768];
        const unsigned short* bufB = bufA + 16384;
        #pragma unroll
        for (int ks = 0; ks < 2; ++ks) {
            f16x8 af[8], bfr[4];
            #pragma unroll
            for (int i = 0; i < 8; ++i) {
                int r = wm * 128 + i * 16 + r15;
                int g = ks * 4 + g4;
                af[i] = *(const f16x8*)&bufA[r * 64 + (g ^ (r & 7)) * 8];
            }
            #pragma unroll
            for (int j = 0; j < 4; ++j) {
                int c = wn * 64 + j * 16 + r15;
                int g = ks * 4 + g4;
                bfr[j] = *(const f16x8*)&bufB[c * 64 + (g ^ (c & 7)) * 8];
            }
            #pragma unroll
            for (int i = 0; i < 8; ++i)
                #pragma unroll
                for (int j = 0; j < 4; ++j)
                    acc[i][j] = __builtin_amdgcn_mfma_f32_16x16x32_f16(
                        af[i], bfr[j], acc[i][j], 0, 0, 0);
        }
        __syncthreads();                // full drain: prefetch landed, reads done
        cur ^= 1;
    }

    // epilogue: C/D layout col=lane&15, row=(lane>>4)*4+reg; store f16
    float rnv[4];
    #pragma unroll
    for (int j = 0; j < 4; ++j)
        rnv[j] = rnz[n0 + wn * 64 + j * 16 + r15];
    #pragma unroll
    for (int i = 0; i < 8; ++i) {
        #pragma unroll
        for (int r = 0; r < 4; ++r) {
            int m = m0 + wm * 128 + i * 16 + g4 * 4 + r;
            float rmv = rmz[m];
            #pragma unroll
            for (int j = 0; j < 4; ++j) {
                int n = n0 + wn * 64 + j * 16 + r15;
                C[(long)m * N + n] = ff16(rmv + rnv[j] - 2.f * acc[i][j][r]);
            }
        }
    }
}

// C[m][n] = epilogue( sum_k A[m][k]*B[n][k] ), NT f16 inputs, strides lda/ldb.
// Minimum-2-phase __syncthreads schedule (proven replay-stable).
// MODE 0: +bias[n] -> f32 C
// MODE 3: relu(+bias[n]) -> compact f16 oQ [m][768]
// MODE 4: combined QKV: seg 0 -> 2-slot q_s + qnp; 1 -> 2-slot k_s + knp;
//         2 -> bf16 oV with SINGLE-TERM K=768
template<int MODE>
__global__ __launch_bounds__(256)
void gemm_mfma(const unsigned short* __restrict__ A, const unsigned short* __restrict__ B,
               const float* __restrict__ bias,
               float* __restrict__ C,
               int M, int N, int Kd, long lda, long ldb,
               unsigned short* __restrict__ oQ, unsigned short* __restrict__ oK,
               unsigned short* __restrict__ oV, float* __restrict__ pn)
{
    // ---- bijective XCD swizzle (T1/m204) ----
    const int nwgx = gridDim.x;
    const int nwg  = nwgx * gridDim.y;
    int lid = blockIdx.y * nwgx + blockIdx.x;
    int qq = nwg >> 3, rr = nwg & 7;
    int xcd = lid & 7, pos = lid >> 3;
    int nlid = (xcd < rr ? xcd * (qq + 1) : rr * (qq + 1) + (xcd - rr) * qq) + pos;
    const int bx = nlid % nwgx;
    const int by = nlid / nwgx;

    __shared__ __align__(16) unsigned short lds[2 * 16384];  // 2 bufs x (A 8192 | B 8192)

    const int tid = threadIdx.x;
    const int lane = tid & 63;
    const int wave = tid >> 6;
    const int wm = wave >> 1, wn = wave & 1;
    const int m0 = by * 128, n0 = bx * 128;
    const int r15 = lane & 15;
    const int g4 = lane >> 4;

    f32x4 acc[4][4] = {};

    long aByte[4], bByte[4];
    int ldsOff[4];
    #pragma unroll
    for (int i = 0; i < 4; ++i) {
        int L = i * 256 + tid;
        int row = L >> 3, ch = L & 7;
        int chs = ch ^ (row & 7);
        aByte[i] = (long)(m0 + row) * lda * 2 + chs * 16;
        bByte[i] = (long)(n0 + row) * ldb * 2 + chs * 16;
        ldsOff[i] = L * 8;
    }

    int NT = Kd >> 6;                          // 36 (or 12 for v segment below)
    if (MODE == 4 && n0 >= 1536) NT = 12;      // v: single-term f16 (hi slots only)

    // prologue: stage tile 0 into buf 0, full drain
    #pragma unroll
    for (int i = 0; i < 4; ++i) {
        gload_lds16((const char*)A + aByte[i], &lds[ldsOff[i]]);
        gload_lds16((const char*)B + bByte[i], &lds[8192 + ldsOff[i]]);
    }
    __syncthreads();

    int cur = 0;
    for (int t = 0; t < NT; ++t) {
        if (t + 1 < NT) {
            long kb = (long)(t + 1) * 128;
            int off = (cur ^ 1) * 16384;
            #pragma unroll
            for (int i = 0; i < 4; ++i) {
                gload_lds16((const char*)A + aByte[i] + kb, &lds[off + ldsOff[i]]);
                gload_lds16((const char*)B + bByte[i] + kb, &lds[off + 8192 + ldsOff[i]]);
            }
        }
        const unsigned short* bufA = &lds[cur * 16384];
        const unsigned short* bufB = bufA + 8192;
        #pragma unroll
        for (int ks = 0; ks < 2; ++ks) {
            f16x8 af[4], bfr[4];
            #pragma unroll
            for (int i = 0; i < 4; ++i) {
                int row = wm * 64 + i * 16 + r15;
                int chs = (ks * 4 + g4) ^ (r15 & 7);
                af[i] = *(const f16x8*)&bufA[row * 64 + chs * 8];
            }
            #pragma unroll
            for (int j = 0; j < 4; ++j) {
                int row = wn * 64 + j * 16 + r15;
                int chs = (ks * 4 + g4) ^ (r15 & 7);
                bfr[j] = *(const f16x8*)&bufB[row * 64 + chs * 8];
            }
            #pragma unroll
            for (int i = 0; i < 4; ++i)
                #pragma unroll
                for (int j = 0; j < 4; ++j)
                    acc[i][j] = __builtin_amdgcn_mfma_f32_16x16x32_f16(
                        af[i], bfr[j], acc[i][j], 0, 0, 0);
        }
        __syncthreads();
        cur ^= 1;
    }

    float bj[4];
    #pragma unroll
    for (int j = 0; j < 4; ++j) {
        int n = n0 + wn * 64 + j * 16 + r15;
        bj[j] = bias[n];
    }

    if (MODE == 0) {
        #pragma unroll
        for (int i = 0; i < 4; ++i) {
            #pragma unroll
            for (int r = 0; r < 4; ++r) {
                int m = m0 + wm * 64 + i * 16 + g4 * 4 + r;
                #pragma unroll
                for (int j = 0; j < 4; ++j) {
                    int n = n0 + wn * 64 + j * 16 + r15;
                    C[(long)m * N + n] = acc[i][j][r] + bj[j];
                }
            }
        }
    }

    if (MODE == 3) {
        #pragma unroll
        for (int i = 0; i < 4; ++i) {
            #pragma unroll
            for (int r = 0; r < 4; ++r) {
                int m = m0 + wm * 64 + i * 16 + g4 * 4 + r;
                #pragma unroll
                for (int j = 0; j < 4; ++j) {
                    int e = n0 + wn * 64 + j * 16 + r15;
                    float xv = fmaxf(acc[i][j][r] + bj[j], 0.f);
                    oQ[(long)m * DD + e] = ff16(xv);
                }
            }
        }
    }

    if (MODE == 4) {
        const int seg = n0 / 768;                       // block-uniform: 0=q 1=k 2=v
        const int e0 = n0 - seg * 768 + wn * 64;
        const int chunk = (bx - seg * 6) * 2 + wn;      // 0..11 within segment
        #pragma unroll
        for (int i = 0; i < 4; ++i) {
            #pragma unroll
            for (int r = 0; r < 4; ++r) {
                int m = m0 + wm * 64 + i * 16 + g4 * 4 + r;
                float vals[4];
                #pragma unroll
                for (int j = 0; j < 4; ++j) vals[j] = acc[i][j][r] + bj[j];
                if (seg == 2) {
                    #pragma unroll
                    for (int j = 0; j < 4; ++j)
                        oV[(long)m * DD + e0 + j * 16 + r15] = rne_bf16(vals[j]);
                } else {
                    unsigned short* os = (seg == 0) ? oQ : oK;
                    #pragma unroll
                    for (int j = 0; j < 4; ++j) {
                        float xv = vals[j];
                        _Float16 hh = (_Float16)xv;
                        float hf = (float)hh;
                        float l = xv - hf;
                        long base = (long)m * QS + e0 + j * 16 + r15;
                        os[base]      = __builtin_bit_cast(unsigned short, hh);
                        os[base + DD] = ff16(l * 64.f);
                    }
                    float s = vals[0]*vals[0] + vals[1]*vals[1]
                            + vals[2]*vals[2] + vals[3]*vals[3];
                    s += __shfl_xor(s, 1); s += __shfl_xor(s, 2);
                    s += __shfl_xor(s, 4); s += __shfl_xor(s, 8);
                    if (r15 == 0)
                        pn[(seg ? (long)BSR * 12 : 0) + (long)m * 12 + chunk] = s;
                }
            }
        }
    }
}

// One WAVE per query row, zero LDS, zero barriers. dist is F16 (scratch).
// Phase 1: streaming per-lane top-8 VALUES (u32 of converted f32).
// Phase 2: threshold selection via narrowed binary search + exact tie-break;
//          wave-uniform tournament fallback on saturation.
// Phase 3: boundary-gap guard (exact fp32 recompute from 2-slot splits) —
//          MARGIN covers f16 storage quantization + gemm error, so the final
//          selected set equals the exact-arithmetic selection.
// Phase 4: rank-based index assignment; bf16 v gather batched 4 rows.
__global__ __launch_bounds__(256)
void select_mean(const unsigned short* __restrict__ dist, const unsigned short* __restrict__ v,
                 const unsigned short* __restrict__ q_s, const unsigned short* __restrict__ k_s,
                 const float* __restrict__ qn, const float* __restrict__ kn,
                 unsigned short* __restrict__ topo_f16)
{
    const int wv = threadIdx.x >> 6;
    const int lane = threadIdx.x & 63;
    const int g = blockIdx.x * 4 + wv;      // global row 0..8191
    const int b = g >> 11;
    const unsigned short* drow = dist + (long)b * SS * SS + (long)(g & (SS - 1)) * SS;
    const unsigned short* vb = v + (long)b * SS * DD;

    float d[32];
    unsigned h0 = 0xffffffffu, h1 = 0xffffffffu, h2 = 0xffffffffu, h3 = 0xffffffffu,
             h4 = 0xffffffffu, h5 = 0xffffffffu, h6 = 0xffffffffu, h7 = 0xffffffffu;
    const u16x4* dr4 = (const u16x4*)drow;
    #pragma unroll
    for (int c = 0; c < 8; ++c) {
        u16x4 tv = dr4[c * 64 + lane];
        #pragma unroll
        for (int i = 0; i < 4; ++i) {
            float x = fmaxf(f16f(tv[i]), 0.f);
            d[c * 4 + i] = x;
            unsigned xv = __builtin_bit_cast(unsigned, x);
            if (xv < h7) {                  // exec-masked sorted insert (values only)
                bool l0 = xv < h0, l1 = xv < h1, l2 = xv < h2, l3 = xv < h3,
                     l4 = xv < h4, l5 = xv < h5, l6 = xv < h6;
                h7 = l6 ? h6 : xv;
                h6 = l6 ? (l5 ? h5 : xv) : h6;
                h5 = l5 ? (l4 ? h4 : xv) : h5;
                h4 = l4 ? (l3 ? h3 : xv) : h4;
                h3 = l3 ? (l2 ? h2 : xv) : h3;
                h2 = l2 ? (l1 ? h1 : xv) : h2;
                h1 = l1 ? (l0 ? h0 : xv) : h1;
                h0 = l0 ? xv : h0;
            }
        }
    }

    unsigned sel = 0;
    float d32v = 0.f, d33v = 0.f;

    // ---- Phase 2: narrowed binary search for the rank-31 value ----
    unsigned lo = h0, hi = h7;
    #pragma unroll
    for (int off = 32; off; off >>= 1) {
        unsigned ol = __shfl_xor(lo, off); lo = ol < lo ? ol : lo;
        unsigned oh = __shfl_xor(hi, off); hi = oh > hi ? oh : hi;
    }
    unsigned diffb = lo ^ hi;
    unsigned Vv; int nb;
    if (diffb == 0) { Vv = lo; nb = -1; }
    else {
        nb = 31 - __builtin_clz(diffb);
        Vv = (nb >= 31) ? 0u : (lo & ~((1u << (nb + 1)) - 1u));
    }
    for (int bit = nb; bit >= 0; --bit) {
        unsigned candv = Vv | (1u << bit);
        int c = (h0 < candv) + (h1 < candv) + (h2 < candv) + (h3 < candv)
              + (h4 < candv) + (h5 < candv) + (h6 < candv) + (h7 < candv);
        int tot = (int)__popcll(__ballot(c & 1))
                + 2 * (int)__popcll(__ballot(c & 2))
                + 4 * (int)__popcll(__ballot(c & 4))
                + 8 * (int)__popcll(__ballot(c & 8));
        if (tot <= 31) Vv = candv;
    }
    bool fallback = __any(h7 <= Vv);

    if (!fallback) {
        int cl = (h0 < Vv) + (h1 < Vv) + (h2 < Vv) + (h3 < Vv)
               + (h4 < Vv) + (h5 < Vv) + (h6 < Vv) + (h7 < Vv);
        int c_lt = (int)__popcll(__ballot(cl & 1))
                 + 2 * (int)__popcll(__ballot(cl & 2))
                 + 4 * (int)__popcll(__ballot(cl & 4))
                 + 8 * (int)__popcll(__ballot(cl & 8));
        #pragma unroll
        for (int s = 0; s < 32; ++s)
            if (__builtin_bit_cast(unsigned, d[s]) < Vv) sel |= 1u << s;
        int need = KNEI - c_lt;
        for (int t2 = 0; t2 < need; ++t2) {
            unsigned mi = 0xffffffffu;
            #pragma unroll
            for (int s = 0; s < 32; ++s) {
                bool eq = (__builtin_bit_cast(unsigned, d[s]) == Vv) && !((sel >> s) & 1u);
                unsigned jj = (unsigned)((s >> 2) * 256 + lane * 4 + (s & 3));
                if (eq && jj < mi) mi = jj;
            }
            #pragma unroll
            for (int off = 32; off; off >>= 1) {
                unsigned o = __shfl_xor(mi, off);
                mi = o < mi ? o : mi;
            }
            if (mi != 0xffffffffu && lane == ((mi >> 2) & 63))
                sel |= 1u << (((mi >> 8) << 2) | (mi & 3));
        }
        d32v = __builtin_bit_cast(float, Vv);
        int ce = (h0 <= Vv) + (h1 <= Vv) + (h2 <= Vv) + (h3 <= Vv)
               + (h4 <= Vv) + (h5 <= Vv) + (h6 <= Vv) + (h7 <= Vv);
        int c_le = (int)__popcll(__ballot(ce & 1))
                 + 2 * (int)__popcll(__ballot(ce & 2))
                 + 4 * (int)__popcll(__ballot(ce & 4))
                 + 8 * (int)__popcll(__ballot(ce & 8));
        if (c_le >= 33) {
            d33v = d32v;
        } else {
            unsigned mv = 0xffffffffu;
            if (h0 > Vv && h0 < mv) mv = h0;
            if (h1 > Vv && h1 < mv) mv = h1;
            if (h2 > Vv && h2 < mv) mv = h2;
            if (h3 > Vv && h3 < mv) mv = h3;
            if (h4 > Vv && h4 < mv) mv = h4;
            if (h5 > Vv && h5 < mv) mv = h5;
            if (h6 > Vv && h6 < mv) mv = h6;
            if (h7 > Vv && h7 < mv) mv = h7;
            #pragma unroll
            for (int off = 32; off; off >>= 1) {
                unsigned o = __shfl_xor(mv, off);
                mv = o < mv ? o : mv;
            }
            d33v = __builtin_bit_cast(float, mv);
        }
    } else {
        // ---- rare saturation path: rebuild u64 keys, 33-iteration tournament ----
        unsigned long long g0 = ~0ull, g1 = ~0ull, g2 = ~0ull, g3 = ~0ull,
                           g4b = ~0ull, g5 = ~0ull, g6 = ~0ull, g7 = ~0ull;
        #pragma unroll
        for (int s = 0; s < 32; ++s) {
            unsigned long long kk =
                ((unsigned long long)__builtin_bit_cast(unsigned, d[s]) << 32)
                | (unsigned)((s >> 2) * 256 + lane * 4 + (s & 3));
            if (kk < g7) {
                bool l0 = kk < g0, l1 = kk < g1, l2 = kk < g2, l3 = kk < g3,
                     l4 = kk < g4b, l5 = kk < g5, l6 = kk < g6;
                g7 = l6 ? g6 : kk;
                g6 = l6 ? (l5 ? g5 : kk) : g6;
                g5 = l5 ? (l4 ? g4b : kk) : g5;
                g4b = l4 ? (l3 ? g3 : kk) : g4b;
                g3 = l3 ? (l2 ? g2 : kk) : g3;
                g2 = l2 ? (l1 ? g1 : kk) : g2;
                g1 = l1 ? (l0 ? g0 : kk) : g1;
                g0 = l0 ? kk : g0;
            }
        }
        int cnt = 0;
        for (int t = 0; t < 33; ++t) {
            unsigned long long best = g0;
            #pragma unroll
            for (int off = 32; off; off >>= 1) {
                unsigned long long o = __shfl_xor(best, off);
                best = o < best ? o : best;
            }
            if (t == 32) {
                d33v = __builtin_bit_cast(float, (unsigned)(best >> 32));
                break;
            }
            int j = (int)(unsigned)best;
            bool won = (lane == ((j >> 2) & 63));
            if (won) sel |= 1u << (((j >> 8) << 2) | (j & 3));
            if (t == 31) d32v = __builtin_bit_cast(float, (unsigned)(best >> 32));

            if (won) cnt++;
            bool needScan = won && (cnt >= 8);
            bool adv = won && (cnt < 8);
            g0 = adv ? g1 : g0;  g1 = adv ? g2 : g1;  g2 = adv ? g3 : g2;
            g3 = adv ? g4b : g3; g4b = adv ? g5 : g4b; g5 = adv ? g6 : g5;
            g6 = adv ? g7 : g6;  g7 = adv ? ~0ull : g7;
            if (__any(needScan)) {
                if (needScan) {
                    float bv = FLT_MAX; int bs = 0; bool found = false;
                    #pragma unroll
                    for (int s = 0; s < 32; ++s) {
                        bool ok = !((sel >> s) & 1u);
                        bool lt = ok && (d[s] < bv);
                        bv = lt ? d[s] : bv; bs = lt ? s : bs; found |= ok;
                    }
                    g0 = found
                       ? (((unsigned long long)__builtin_bit_cast(unsigned, bv) << 32)
                          | (unsigned)((bs >> 2) * 256 + lane * 4 + (bs & 3)))
                       : ~0ull;
                }
            }
        }
    }

    // ---- Phase 3: boundary-gap guard (exact fp32 recompute for the window) ----
    if (d33v - d32v < MARGIN) {
        float lo2 = d32v - MARGIN, hi2 = d33v + MARGIN;
        unsigned cand = 0;
        #pragma unroll
        for (int s = 0; s < 32; ++s)
            if (d[s] >= lo2 && d[s] <= hi2) cand |= 1u << s;

        const unsigned short* qrow = q_s + (long)g * QS;
        const u16x4* qh = (const u16x4*)&qrow[lane * 12];
        const u16x4* ql = (const u16x4*)&qrow[DD + lane * 12];
        #pragma unroll
        for (int s = 0; s < 32; ++s) {
            unsigned long long m = __ballot((cand >> s) & 1u);
            while (m) {
                int l2 = __ffsll(m) - 1;
                m &= m - 1;
                int j = (s >> 2) * 256 + l2 * 4 + (s & 3);
                const unsigned short* krow = k_s + ((long)b * SS + j) * QS;
                const u16x4* kh = (const u16x4*)&krow[lane * 12];
                const u16x4* kl = (const u16x4*)&krow[DD + lane * 12];
                float part = 0.f;
                #pragma unroll
                for (int c = 0; c < 3; ++c) {
                    u16x4 qa = qh[c], qb = ql[c], ka = kh[c], kb2 = kl[c];
                    #pragma unroll
                    for (int e = 0; e < 4; ++e) {
                        float qv = f16f(qa[e]) + f16f(qb[e]) * 0.015625f;
                        float kv = f16f(ka[e]) + f16f(kb2[e]) * 0.015625f;
                        part = fmaf(qv, kv, part);
                    }
                }
                #pragma unroll
                for (int off = 32; off; off >>= 1) part += __shfl_xor(part, off);
                float dd = qn[g] + kn[(long)b * SS + j] - 2.f * part;
                dd = fmaxf(dd, 0.f);
                if (lane == l2) d[s] = dd;
            }
        }

        sel &= ~cand;
        int C = 0;
        #pragma unroll
        for (int s = 0; s < 32; ++s) C += (int)__popcll(__ballot((sel >> s) & 1u));
        int need = KNEI - C;
        for (int t = 0; t < need; ++t) {
            unsigned long long best = ~0ull;
            #pragma unroll
            for (int s = 0; s < 32; ++s) {
                if (((cand >> s) & 1u) && !((sel >> s) & 1u)) {
                    unsigned long long key =
                        ((unsigned long long)__builtin_bit_cast(unsigned, d[s]) << 32)
                        | (unsigned)((s >> 2) * 256 + lane * 4 + (s & 3));
                    best = key < best ? key : best;
                }
            }
            #pragma unroll
            for (int off = 32; off; off >>= 1) {
                unsigned long long o = __shfl_xor(best, off);
                best = o < best ? o : best;
            }
            if (best != ~0ull) {
                int j = (int)(unsigned)best;
                if (lane == ((j >> 2) & 63)) sel |= 1u << (((j >> 8) << 2) | (j & 3));
            }
        }
    }

    // ---- Phase 4: rank-based selected-index assignment + batched bf16 gather ----
    int myj = 0;
    {
        int target = lane & 31;            // lane p (and p+32) own the p-th selected index
        int cum = 0;
        #pragma unroll
        for (int s = 0; s < 32; ++s) {
            unsigned long long m = __ballot((sel >> s) & 1u);
            int c = (int)__popcll(m);
            if (target >= cum && target < cum + c) {
                int nth = target - cum;
                unsigned long long mm = m;
                int base = 0;
                int c32 = (int)__popcll(mm & 0xffffffffull);
                if (nth >= c32) { nth -= c32; mm >>= 32; base += 32; }
                int c16 = (int)__popcll(mm & 0xffffull);
                if (nth >= c16) { nth -= c16; mm >>= 16; base += 16; }
                int c8 = (int)__popcll(mm & 0xffull);
                if (nth >= c8) { nth -= c8; mm >>= 8; base += 8; }
                int c4 = (int)__popcll(mm & 0xfull);
                if (nth >= c4) { nth -= c4; mm >>= 4; base += 4; }
                int c2 = (int)__popcll(mm & 0x3ull);
                if (nth >= c2) { nth -= c2; mm >>= 2; base += 2; }
                int c1 = (int)(mm & 1ull);
                if (nth >= c1) { base += 1; }
                myj = (s >> 2) * 256 + base * 4 + (s & 3);
            }
            cum += c;
        }
    }
    f32x4 a0 = {0.f, 0.f, 0.f, 0.f}, a1 = a0, a2 = a0;
    #pragma unroll
    for (int tb = 0; tb < 8; ++tb) {
        u16x4 r0[4], r1[4], r2[4];
        #pragma unroll
        for (int u = 0; u < 4; ++u) {
            int j = __shfl(myj, tb * 4 + u);
            const u16x4* vr = (const u16x4*)(vb + (long)j * DD);
            r0[u] = vr[lane];
            r1[u] = vr[lane + 64];
            r2[u] = vr[lane + 128];
        }
        #pragma unroll
        for (int u = 0; u < 4; ++u) {
            #pragma unroll
            for (int e = 0; e < 4; ++e) {
                a0[e] += bf16f(r0[u][e]);
                a1[e] += bf16f(r1[u][e]);
                a2[e] += bf16f(r2[u][e]);
            }
        }
    }
    const float sc = 1.0f / 32.0f;
    unsigned short* trow = topo_f16 + (long)g * DD;
    #pragma unroll
    for (int c = 0; c < 3; ++c) {
        f32x4 x = (c == 0) ? a0 : (c == 1) ? a1 : a2;
        u16x4 hi4;
        #pragma unroll
        for (int e = 0; e < 4; ++e) hi4[e] = ff16(x[e] * sc);
        *(u16x4*)&trow[c * 256 + lane * 4] = hi4;
    }
}

extern "C" void kernel_launch(void* const* d_in, const int* in_sizes, int n_in,
                              void* d_out, int out_size, void* d_ws, size_t ws_size,
                              hipStream_t stream)
{
    const float* hs = (const float*)d_in[0];
    const float* Wq = (const float*)d_in[1];
    const float* bq = (const float*)d_in[2];
    const float* Wk = (const float*)d_in[3];
    const float* bk = (const float*)d_in[4];
    const float* Wv = (const float*)d_in[5];
    const float* bv = (const float*)d_in[6];
    const float* W1 = (const float*)d_in[7];
    const float* b1 = (const float*)d_in[8];
    const float* W2 = (const float*)d_in[9];
    const float* b2 = (const float*)d_in[10];
    float* out = (float*)d_out;

    // ---- workspace layout (peak ~147 MB), time-overlaid ----
    char* w = (char*)d_ws;
    const long DISTB = (long)BB * SS * SS * 2;        // 33,554,432 (f16 dist)
    const long VB    = (long)BSR * DD * 2;            // 12,582,912 (bf16 v)
    const long WSPL  = (long)DD * K2;                 // elems per 3-term split weight

    unsigned short* dist   = (unsigned short*)w;                      // [0, 33.6M)
    unsigned short* h_f16  = (unsigned short*)w;                      // overlays dead dist
    unsigned short* v      = (unsigned short*)(w + DISTB);            // bf16 v
    unsigned short* q_s    = (unsigned short*)(w + DISTB + VB);       // 2-slot
    unsigned short* k_s    = q_s + (long)BSR * QS;                    // 2-slot
    unsigned short* hs_s   = k_s + (long)BSR * QS;                    // 3-term A-layout
    unsigned short* topo_f16 = hs_s;                                  // overlays dead hs_s
    unsigned short* Wqkv_s = hs_s + (long)BSR * K2;                   // 3 weight splits adjacent
    char* tail  = (char*)(Wqkv_s + 3 * WSPL);
    float* qn   = (float*)tail;                        // 8192
    float* kn   = qn + BSR;                            // 8192
    float* pn   = kn + BSR;                            // qnp[8192][12] + knp[8192][12]
    float* bqkv = pn + (long)2 * BSR * 12;             // 2304
    unsigned short* W12 = (unsigned short*)(bqkv + 2304);
    unsigned short* W1_f16 = W12;
    unsigned short* W2_f16 = W12 + (long)DD * DD;      // +2.25 MB

    dim3 blk(256);

    // merged prologue: weight splits + hs split + W1/W2 conv + bias concat
    prep<<<4521, blk, 0, stream>>>(Wq, Wk, Wv, hs, W1, W2, bq, bk, bv,
                                   Wqkv_s, hs_s, W1_f16, W2_f16, bqkv);

    // fused QKV gemm: q -> 2-slot q_s + norms, k -> 2-slot k_s + norms, v -> bf16 (K=768)
    gemm_mfma<4><<<dim3(2304 / 128, BSR / 128, 1), blk, 0, stream>>>(
        hs_s, Wqkv_s, bqkv, nullptr, BSR, 2304, K2, K2, K2,
        q_s, k_s, v, pn);

    finish_norms<<<(2 * BSR) / 256, blk, 0, stream>>>(pn, qn, kn);

    // squared distance matrix per batch: single-term f16 inputs, F16 output
    gemm256_dist<<<dim3(SS / 256, SS / 256, BB), dim3(512), 0, stream>>>(
        q_s, k_s, qn, kn, dist, SS, DD, QS, QS,
        (long)SS * QS, (long)SS * QS, (long)SS * SS, SS);

    select_mean<<<BSR / 4, blk, 0, stream>>>(dist, v, q_s, k_s, qn, kn, topo_f16);

    // MLP single-term f16: gemm1 -> compact f16 h (relu fused), gemm2 -> f32 out
    gemm_mfma<3><<<dim3(DD / 128, BSR / 128, 1), blk, 0, stream>>>(
        topo_f16, W1_f16, b1, nullptr, BSR, DD, DD, DD, DD,
        h_f16, nullptr, nullptr, nullptr);
    gemm_mfma<0><<<dim3(DD / 128, BSR / 128, 1), blk, 0, stream>>>(
        h_f16, W2_f16, b2, out, BSR, DD, DD, DD, DD,
        nullptr, nullptr, nullptr, nullptr);
}

// Round 21
// 241.151 us; speedup vs baseline: 1.0758x; 1.0758x over previous
//
#include <hip/hip_runtime.h>
#include <float.h>

#define DD 768
#define SS 2048
#define BB 4
#define BSR (BB*SS)   // 8192 total rows
#define KNEI 32
#define K2 (3*DD)     // 2304: [hi | x | y] split concat along K (hs_s only)
#define QS (2*DD)     // 1536: 2-slot q_s/k_s layout [h, l*2^6]
#define MARGIN 0.12f  // >=6 sigma of single-term f16 pairwise dist error

typedef __attribute__((ext_vector_type(8))) _Float16 f16x8;
typedef __attribute__((ext_vector_type(4))) float f32x4;
typedef __attribute__((ext_vector_type(8))) unsigned short u16x8;
typedef __attribute__((ext_vector_type(4))) unsigned short u16x4;

__device__ __forceinline__ float f16f(unsigned short u) {
    return (float)__builtin_bit_cast(_Float16, u);
}
__device__ __forceinline__ unsigned short ff16(float x) {
    return __builtin_bit_cast(unsigned short, (_Float16)x);
}
__device__ __forceinline__ unsigned short rne_bf16(float x) {
    unsigned u = __builtin_bit_cast(unsigned, x);
    unsigned r = u + 0x7FFFu + ((u >> 16) & 1u);
    return (unsigned short)(r >> 16);
}
__device__ __forceinline__ float bf16f(unsigned short h) {
    return __builtin_bit_cast(float, (unsigned)h << 16);
}

__device__ __forceinline__ void gload_lds16(const void* g, void* l) {
    __builtin_amdgcn_global_load_lds(
        (const __attribute__((address_space(1))) unsigned int*)g,
        (__attribute__((address_space(3))) unsigned int*)l, 16, 0, 0);
}

// fp32 -> 3-slot f16 split body (8 elems at flat chunk id `idx`).
// A-layout (LO_SLOT=1): [h, l*2^6, h*2^-6];  B-layout (LO_SLOT=2): [h, h*2^-6, l*2^6]
template<int LO_SLOT>
__device__ __forceinline__ void split_body(const float* __restrict__ in,
                                           unsigned short* __restrict__ out,
                                           int idx, int Kc)
{
    int perRow = Kc >> 3;
    int row = idx / perRow, c8 = idx - row * perRow;
    const float* src = in + (long)row * Kc + c8 * 8;
    f32x4 x0 = *(const f32x4*)&src[0];
    f32x4 x1 = *(const f32x4*)&src[4];
    u16x8 hi, lsc, hsc;
    #pragma unroll
    for (int e = 0; e < 8; ++e) {
        float xv = (e < 4) ? x0[e] : x1[e - 4];
        _Float16 h = (_Float16)xv;
        float hf = (float)h;
        float l = xv - hf;
        hi[e]  = __builtin_bit_cast(unsigned short, h);
        lsc[e] = ff16(l * 64.f);
        hsc[e] = ff16(hf * 0.015625f);
    }
    long base = (long)row * (3 * Kc) + c8 * 8;
    *(u16x8*)&out[base] = hi;
    *(u16x8*)&out[base + Kc]     = (LO_SLOT == 1) ? lsc : hsc;
    *(u16x8*)&out[base + 2 * Kc] = (LO_SLOT == 1) ? hsc : lsc;
}

__device__ __forceinline__ void conv_body(const float* __restrict__ in,
                                          unsigned short* __restrict__ out, int idx)
{
    const float* src = in + (long)idx * 8;
    f32x4 x0 = *(const f32x4*)&src[0];
    f32x4 x1 = *(const f32x4*)&src[4];
    u16x8 o;
    #pragma unroll
    for (int e = 0; e < 8; ++e) {
        float xv = (e < 4) ? x0[e] : x1[e - 4];
        o[e] = ff16(xv);
    }
    *(u16x8*)&out[(long)idx * 8] = o;
}

// ---- merged prologue: 3 weight splits + hs split + 2 MLP convs + bias concat ----
__global__ __launch_bounds__(256)
void prep(const float* __restrict__ Wq, const float* __restrict__ Wk,
          const float* __restrict__ Wv, const float* __restrict__ hs,
          const float* __restrict__ W1, const float* __restrict__ W2,
          const float* __restrict__ bq, const float* __restrict__ bk,
          const float* __restrict__ bv,
          unsigned short* __restrict__ Wqkv_s, unsigned short* __restrict__ hs_s,
          unsigned short* __restrict__ W1_f16, unsigned short* __restrict__ W2_f16,
          float* __restrict__ bqkv)
{
    const long WSPL = (long)DD * K2;
    int bid = blockIdx.x;
    int tid = threadIdx.x;
    if (bid < 864) {
        int which = bid / 288, sub = bid - which * 288;
        const float* src = (which == 0) ? Wq : (which == 1) ? Wk : Wv;
        split_body<2>(src, Wqkv_s + (long)which * WSPL, sub * 256 + tid, DD);
    } else if (bid < 3936) {
        split_body<1>(hs, hs_s, (bid - 864) * 256 + tid, DD);
    } else if (bid < 4224) {
        conv_body(W1, W1_f16, (bid - 3936) * 256 + tid);
    } else if (bid < 4512) {
        conv_body(W2, W2_f16, (bid - 4224) * 256 + tid);
    } else {
        int i = (bid - 4512) * 256 + tid;
        if (i < 768) bqkv[i] = bq[i];
        else if (i < 1536) bqkv[i] = bk[i - 768];
        else if (i < 2304) bqkv[i] = bv[i - 1536];
    }
}

// pn rows: qnp[8192][12] then knp[8192][12] contiguous; fixed-order sum.
__global__ __launch_bounds__(256)
void finish_norms(const float* __restrict__ pn, float* __restrict__ qn, float* __restrict__ kn)
{
    int row = blockIdx.x * 256 + threadIdx.x;   // 0..16383
    const float* p = pn + (long)row * 12;
    float s = 0.f;
    #pragma unroll
    for (int c = 0; c < 12; ++c) s += p[c];
    if (row < BSR) qn[row] = s; else kn[row - BSR] = s;
}

// ---------------------------------------------------------------------------
// 256x256-tile distance GEMM, minimum-2-phase __syncthreads schedule
// (prefetch next tile into buf^1, compute buf[cur], ONE __syncthreads/tile).
// Single-term f16: Kd=768 (hi slots only), row stride lda/ldb = QS.
// ---------------------------------------------------------------------------
__global__ __launch_bounds__(512)
void gemm256_dist(const unsigned short* __restrict__ A, const unsigned short* __restrict__ B,
                  const float* __restrict__ rm, const float* __restrict__ rn,
                  float* __restrict__ C,
                  int N, int Kd, long lda, long ldb,
                  long sA, long sB, long sC, long sR)
{
    const int z = blockIdx.z;
    A += (long)z * sA;
    B += (long)z * sB;
    C += (long)z * sC;
    const float* rmz = rm + (long)z * sR;
    const float* rnz = rn + (long)z * sR;

    // bijective XCD swizzle over the 64 blocks of this batch
    int lid = blockIdx.y * gridDim.x + blockIdx.x;
    int xcd = lid & 7, pos = lid >> 3;
    int nlid = xcd * 8 + pos;
    const int bx = nlid & 7, by = nlid >> 3;

    __shared__ __align__(16) unsigned short lds[2 * 32768];  // 2 bufs x (A 16384 | B 16384) f16

    const int tid = threadIdx.x;
    const int lane = tid & 63;
    const int wave = tid >> 6;
    const int wm = wave >> 2, wn = wave & 3;   // 2 x 4 wave grid
    const int m0 = by * 256, n0 = bx * 256;
    const int r15 = lane & 15;
    const int g4 = lane >> 4;

    f32x4 acc[8][4] = {};

    long aB[4], bB[4];
    int lof[4];
    #pragma unroll
    for (int i = 0; i < 4; ++i) {
        int L = i * 512 + tid;          // 0..2047 chunk id (16B chunks)
        int row = L >> 3, ch = L & 7;
        int chs = ch ^ (row & 7);
        aB[i] = (long)(m0 + row) * lda * 2 + chs * 16;
        bB[i] = (long)(n0 + row) * ldb * 2 + chs * 16;
        lof[i] = L * 8;
    }

    const int NT = Kd >> 6;             // 12 K-tiles of 64

    // prologue: stage tile 0 into buf 0, full drain
    #pragma unroll
    for (int i = 0; i < 4; ++i) {
        gload_lds16((const char*)A + aB[i], &lds[lof[i]]);
        gload_lds16((const char*)B + bB[i], &lds[16384 + lof[i]]);
    }
    __syncthreads();

    int cur = 0;
    for (int t = 0; t < NT; ++t) {
        if (t + 1 < NT) {               // prefetch next tile into the other buffer
            long kb = (long)(t + 1) * 128;
            int off = (cur ^ 1) * 32768;
            #pragma unroll
            for (int i = 0; i < 4; ++i) {
                gload_lds16((const char*)A + aB[i] + kb, &lds[off + lof[i]]);
                gload_lds16((const char*)B + bB[i] + kb, &lds[off + 16384 + lof[i]]);
            }
        }
        const unsigned short* bufA = &lds[cur * 32768];
        const unsigned short* bufB = bufA + 16384;
        #pragma unroll
        for (int ks = 0; ks < 2; ++ks) {
            f16x8 af[8], bfr[4];
            #pragma unroll
            for (int i = 0; i < 8; ++i) {
                int r = wm * 128 + i * 16 + r15;
                int g = ks * 4 + g4;
                af[i] = *(const f16x8*)&bufA[r * 64 + (g ^ (r & 7)) * 8];
            }
            #pragma unroll
            for (int j = 0; j < 4; ++j) {
                int c = wn * 64 + j * 16 + r15;
                int g = ks * 4 + g4;
                bfr[j] = *(const f16x8*)&bufB[c * 64 + (g ^ (c & 7)) * 8];
            }
            #pragma unroll
            for (int i = 0; i < 8; ++i)
                #pragma unroll
                for (int j = 0; j < 4; ++j)
                    acc[i][j] = __builtin_amdgcn_mfma_f32_16x16x32_f16(
                        af[i], bfr[j], acc[i][j], 0, 0, 0);
        }
        __syncthreads();                // full drain: prefetch landed, reads done
        cur ^= 1;
    }

    // epilogue: C/D layout col=lane&15, row=(lane>>4)*4+reg
    float rnv[4];
    #pragma unroll
    for (int j = 0; j < 4; ++j)
        rnv[j] = rnz[n0 + wn * 64 + j * 16 + r15];
    #pragma unroll
    for (int i = 0; i < 8; ++i) {
        #pragma unroll
        for (int r = 0; r < 4; ++r) {
            int m = m0 + wm * 128 + i * 16 + g4 * 4 + r;
            float rmv = rmz[m];
            #pragma unroll
            for (int j = 0; j < 4; ++j) {
                int n = n0 + wn * 64 + j * 16 + r15;
                C[(long)m * N + n] = rmv + rnv[j] - 2.f * acc[i][j][r];
            }
        }
    }
}

// C[m][n] = epilogue( sum_k A[m][k]*B[n][k] ), NT f16 inputs, strides lda/ldb.
// Minimum-2-phase __syncthreads schedule (proven replay-stable).
// MODE 0: +bias[n] -> f32 C
// MODE 3: relu(+bias[n]) -> compact f16 oQ [m][768]
// MODE 4: combined QKV: seg 0 -> 2-slot q_s + qnp; 1 -> 2-slot k_s + knp;
//         2 -> bf16 oV with SINGLE-TERM K=768
template<int MODE>
__global__ __launch_bounds__(256)
void gemm_mfma(const unsigned short* __restrict__ A, const unsigned short* __restrict__ B,
               const float* __restrict__ bias,
               float* __restrict__ C,
               int M, int N, int Kd, long lda, long ldb,
               unsigned short* __restrict__ oQ, unsigned short* __restrict__ oK,
               unsigned short* __restrict__ oV, float* __restrict__ pn)
{
    // ---- bijective XCD swizzle (T1/m204) ----
    const int nwgx = gridDim.x;
    const int nwg  = nwgx * gridDim.y;
    int lid = blockIdx.y * nwgx + blockIdx.x;
    int qq = nwg >> 3, rr = nwg & 7;
    int xcd = lid & 7, pos = lid >> 3;
    int nlid = (xcd < rr ? xcd * (qq + 1) : rr * (qq + 1) + (xcd - rr) * qq) + pos;
    const int bx = nlid % nwgx;
    const int by = nlid / nwgx;

    __shared__ __align__(16) unsigned short lds[2 * 16384];  // 2 bufs x (A 8192 | B 8192)

    const int tid = threadIdx.x;
    const int lane = tid & 63;
    const int wave = tid >> 6;
    const int wm = wave >> 1, wn = wave & 1;
    const int m0 = by * 128, n0 = bx * 128;
    const int r15 = lane & 15;
    const int g4 = lane >> 4;

    f32x4 acc[4][4] = {};

    long aByte[4], bByte[4];
    int ldsOff[4];
    #pragma unroll
    for (int i = 0; i < 4; ++i) {
        int L = i * 256 + tid;
        int row = L >> 3, ch = L & 7;
        int chs = ch ^ (row & 7);
        aByte[i] = (long)(m0 + row) * lda * 2 + chs * 16;
        bByte[i] = (long)(n0 + row) * ldb * 2 + chs * 16;
        ldsOff[i] = L * 8;
    }

    int NT = Kd >> 6;                          // 36 (or 12 for v segment below)
    if (MODE == 4 && n0 >= 1536) NT = 12;      // v: single-term f16 (hi slots only)

    // prologue: stage tile 0 into buf 0, full drain
    #pragma unroll
    for (int i = 0; i < 4; ++i) {
        gload_lds16((const char*)A + aByte[i], &lds[ldsOff[i]]);
        gload_lds16((const char*)B + bByte[i], &lds[8192 + ldsOff[i]]);
    }
    __syncthreads();

    int cur = 0;
    for (int t = 0; t < NT; ++t) {
        if (t + 1 < NT) {
            long kb = (long)(t + 1) * 128;
            int off = (cur ^ 1) * 16384;
            #pragma unroll
            for (int i = 0; i < 4; ++i) {
                gload_lds16((const char*)A + aByte[i] + kb, &lds[off + ldsOff[i]]);
                gload_lds16((const char*)B + bByte[i] + kb, &lds[off + 8192 + ldsOff[i]]);
            }
        }
        const unsigned short* bufA = &lds[cur * 16384];
        const unsigned short* bufB = bufA + 8192;
        #pragma unroll
        for (int ks = 0; ks < 2; ++ks) {
            f16x8 af[4], bfr[4];
            #pragma unroll
            for (int i = 0; i < 4; ++i) {
                int row = wm * 64 + i * 16 + r15;
                int chs = (ks * 4 + g4) ^ (r15 & 7);
                af[i] = *(const f16x8*)&bufA[row * 64 + chs * 8];
            }
            #pragma unroll
            for (int j = 0; j < 4; ++j) {
                int row = wn * 64 + j * 16 + r15;
                int chs = (ks * 4 + g4) ^ (r15 & 7);
                bfr[j] = *(const f16x8*)&bufB[row * 64 + chs * 8];
            }
            #pragma unroll
            for (int i = 0; i < 4; ++i)
                #pragma unroll
                for (int j = 0; j < 4; ++j)
                    acc[i][j] = __builtin_amdgcn_mfma_f32_16x16x32_f16(
                        af[i], bfr[j], acc[i][j], 0, 0, 0);
        }
        __syncthreads();
        cur ^= 1;
    }

    float bj[4];
    #pragma unroll
    for (int j = 0; j < 4; ++j) {
        int n = n0 + wn * 64 + j * 16 + r15;
        bj[j] = bias[n];
    }

    if (MODE == 0) {
        #pragma unroll
        for (int i = 0; i < 4; ++i) {
            #pragma unroll
            for (int r = 0; r < 4; ++r) {
                int m = m0 + wm * 64 + i * 16 + g4 * 4 + r;
                #pragma unroll
                for (int j = 0; j < 4; ++j) {
                    int n = n0 + wn * 64 + j * 16 + r15;
                    C[(long)m * N + n] = acc[i][j][r] + bj[j];
                }
            }
        }
    }

    if (MODE == 3) {
        #pragma unroll
        for (int i = 0; i < 4; ++i) {
            #pragma unroll
            for (int r = 0; r < 4; ++r) {
                int m = m0 + wm * 64 + i * 16 + g4 * 4 + r;
                #pragma unroll
                for (int j = 0; j < 4; ++j) {
                    int e = n0 + wn * 64 + j * 16 + r15;
                    float xv = fmaxf(acc[i][j][r] + bj[j], 0.f);
                    oQ[(long)m * DD + e] = ff16(xv);
                }
            }
        }
    }

    if (MODE == 4) {
        const int seg = n0 / 768;                       // block-uniform: 0=q 1=k 2=v
        const int e0 = n0 - seg * 768 + wn * 64;
        const int chunk = (bx - seg * 6) * 2 + wn;      // 0..11 within segment
        #pragma unroll
        for (int i = 0; i < 4; ++i) {
            #pragma unroll
            for (int r = 0; r < 4; ++r) {
                int m = m0 + wm * 64 + i * 16 + g4 * 4 + r;
                float vals[4];
                #pragma unroll
                for (int j = 0; j < 4; ++j) vals[j] = acc[i][j][r] + bj[j];
                if (seg == 2) {
                    #pragma unroll
                    for (int j = 0; j < 4; ++j)
                        oV[(long)m * DD + e0 + j * 16 + r15] = rne_bf16(vals[j]);
                } else {
                    unsigned short* os = (seg == 0) ? oQ : oK;
                    #pragma unroll
                    for (int j = 0; j < 4; ++j) {
                        float xv = vals[j];
                        _Float16 hh = (_Float16)xv;
                        float hf = (float)hh;
                        float l = xv - hf;
                        long base = (long)m * QS + e0 + j * 16 + r15;
                        os[base]      = __builtin_bit_cast(unsigned short, hh);
                        os[base + DD] = ff16(l * 64.f);
                    }
                    float s = vals[0]*vals[0] + vals[1]*vals[1]
                            + vals[2]*vals[2] + vals[3]*vals[3];
                    s += __shfl_xor(s, 1); s += __shfl_xor(s, 2);
                    s += __shfl_xor(s, 4); s += __shfl_xor(s, 8);
                    if (r15 == 0)
                        pn[(seg ? (long)BSR * 12 : 0) + (long)m * 12 + chunk] = s;
                }
            }
        }
    }
}

// One WAVE per query row, zero LDS, zero barriers.
// Phase 1: streaming per-lane top-8 VALUES (u32, exec-masked sorted insert).
// Phase 2: threshold selection via common-prefix-narrowed binary search on
//          value bits (bitplane ballots); exact tie-break by index from d[];
//          wave-uniform fallback rebuilds u64 keys + 33-iteration tournament
//          on saturation (expected never).
// Phase 3: boundary-gap guard (exact fp32 recompute from 2-slot splits).
// Phase 4: rank-based index assignment; bf16 v gather batched 4 rows.
// Writes COMPACT f16 topo [g][768].
__global__ __launch_bounds__(256)
void select_mean(const float* __restrict__ dist, const unsigned short* __restrict__ v,
                 const unsigned short* __restrict__ q_s, const unsigned short* __restrict__ k_s,
                 const float* __restrict__ qn, const float* __restrict__ kn,
                 unsigned short* __restrict__ topo_f16)
{
    const int wv = threadIdx.x >> 6;
    const int lane = threadIdx.x & 63;
    const int g = blockIdx.x * 4 + wv;      // global row 0..8191
    const int b = g >> 11;
    const float* drow = dist + (long)b * SS * SS + (long)(g & (SS - 1)) * SS;
    const unsigned short* vb = v + (long)b * SS * DD;

    float d[32];
    unsigned h0 = 0xffffffffu, h1 = 0xffffffffu, h2 = 0xffffffffu, h3 = 0xffffffffu,
             h4 = 0xffffffffu, h5 = 0xffffffffu, h6 = 0xffffffffu, h7 = 0xffffffffu;
    const f32x4* dr4 = (const f32x4*)drow;
    #pragma unroll
    for (int c = 0; c < 8; ++c) {
        f32x4 tv = dr4[c * 64 + lane];
        #pragma unroll
        for (int i = 0; i < 4; ++i) {
            float x = fmaxf(tv[i], 0.f);
            d[c * 4 + i] = x;
            unsigned xv = __builtin_bit_cast(unsigned, x);
            if (xv < h7) {                  // exec-masked sorted insert (values only)
                bool l0 = xv < h0, l1 = xv < h1, l2 = xv < h2, l3 = xv < h3,
                     l4 = xv < h4, l5 = xv < h5, l6 = xv < h6;
                h7 = l6 ? h6 : xv;
                h6 = l6 ? (l5 ? h5 : xv) : h6;
                h5 = l5 ? (l4 ? h4 : xv) : h5;
                h4 = l4 ? (l3 ? h3 : xv) : h4;
                h3 = l3 ? (l2 ? h2 : xv) : h3;
                h2 = l2 ? (l1 ? h1 : xv) : h2;
                h1 = l1 ? (l0 ? h0 : xv) : h1;
                h0 = l0 ? xv : h0;
            }
        }
    }

    unsigned sel = 0;
    float d32v = 0.f, d33v = 0.f;

    // ---- Phase 2: narrowed binary search for the rank-31 value ----
    unsigned lo = h0, hi = h7;
    #pragma unroll
    for (int off = 32; off; off >>= 1) {
        unsigned ol = __shfl_xor(lo, off); lo = ol < lo ? ol : lo;
        unsigned oh = __shfl_xor(hi, off); hi = oh > hi ? oh : hi;
    }
    unsigned diffb = lo ^ hi;
    unsigned Vv; int nb;
    if (diffb == 0) { Vv = lo; nb = -1; }
    else {
        nb = 31 - __builtin_clz(diffb);
        Vv = (nb >= 31) ? 0u : (lo & ~((1u << (nb + 1)) - 1u));
    }
    for (int bit = nb; bit >= 0; --bit) {
        unsigned candv = Vv | (1u << bit);
        int c = (h0 < candv) + (h1 < candv) + (h2 < candv) + (h3 < candv)
              + (h4 < candv) + (h5 < candv) + (h6 < candv) + (h7 < candv);
        int tot = (int)__popcll(__ballot(c & 1))
                + 2 * (int)__popcll(__ballot(c & 2))
                + 4 * (int)__popcll(__ballot(c & 4))
                + 8 * (int)__popcll(__ballot(c & 8));
        if (tot <= 31) Vv = candv;
    }
    bool fallback = __any(h7 <= Vv);

    if (!fallback) {
        int cl = (h0 < Vv) + (h1 < Vv) + (h2 < Vv) + (h3 < Vv)
               + (h4 < Vv) + (h5 < Vv) + (h6 < Vv) + (h7 < Vv);
        int c_lt = (int)__popcll(__ballot(cl & 1))
                 + 2 * (int)__popcll(__ballot(cl & 2))
                 + 4 * (int)__popcll(__ballot(cl & 4))
                 + 8 * (int)__popcll(__ballot(cl & 8));
        #pragma unroll
        for (int s = 0; s < 32; ++s)
            if (__builtin_bit_cast(unsigned, d[s]) < Vv) sel |= 1u << s;
        int need = KNEI - c_lt;
        for (int t2 = 0; t2 < need; ++t2) {
            unsigned mi = 0xffffffffu;
            #pragma unroll
            for (int s = 0; s < 32; ++s) {
                bool eq = (__builtin_bit_cast(unsigned, d[s]) == Vv) && !((sel >> s) & 1u);
                unsigned jj = (unsigned)((s >> 2) * 256 + lane * 4 + (s & 3));
                if (eq && jj < mi) mi = jj;
            }
            #pragma unroll
            for (int off = 32; off; off >>= 1) {
                unsigned o = __shfl_xor(mi, off);
                mi = o < mi ? o : mi;
            }
            if (mi != 0xffffffffu && lane == ((mi >> 2) & 63))
                sel |= 1u << (((mi >> 8) << 2) | (mi & 3));
        }
        d32v = __builtin_bit_cast(float, Vv);
        int ce = (h0 <= Vv) + (h1 <= Vv) + (h2 <= Vv) + (h3 <= Vv)
               + (h4 <= Vv) + (h5 <= Vv) + (h6 <= Vv) + (h7 <= Vv);
        int c_le = (int)__popcll(__ballot(ce & 1))
                 + 2 * (int)__popcll(__ballot(ce & 2))
                 + 4 * (int)__popcll(__ballot(ce & 4))
                 + 8 * (int)__popcll(__ballot(ce & 8));
        if (c_le >= 33) {
            d33v = d32v;
        } else {
            unsigned mv = 0xffffffffu;
            if (h0 > Vv && h0 < mv) mv = h0;
            if (h1 > Vv && h1 < mv) mv = h1;
            if (h2 > Vv && h2 < mv) mv = h2;
            if (h3 > Vv && h3 < mv) mv = h3;
            if (h4 > Vv && h4 < mv) mv = h4;
            if (h5 > Vv && h5 < mv) mv = h5;
            if (h6 > Vv && h6 < mv) mv = h6;
            if (h7 > Vv && h7 < mv) mv = h7;
            #pragma unroll
            for (int off = 32; off; off >>= 1) {
                unsigned o = __shfl_xor(mv, off);
                mv = o < mv ? o : mv;
            }
            d33v = __builtin_bit_cast(float, mv);
        }
    } else {
        // ---- rare saturation path: rebuild u64 keys, 33-iteration tournament ----
        unsigned long long g0 = ~0ull, g1 = ~0ull, g2 = ~0ull, g3 = ~0ull,
                           g4b = ~0ull, g5 = ~0ull, g6 = ~0ull, g7 = ~0ull;
        #pragma unroll
        for (int s = 0; s < 32; ++s) {
            unsigned long long kk =
                ((unsigned long long)__builtin_bit_cast(unsigned, d[s]) << 32)
                | (unsigned)((s >> 2) * 256 + lane * 4 + (s & 3));
            if (kk < g7) {
                bool l0 = kk < g0, l1 = kk < g1, l2 = kk < g2, l3 = kk < g3,
                     l4 = kk < g4b, l5 = kk < g5, l6 = kk < g6;
                g7 = l6 ? g6 : kk;
                g6 = l6 ? (l5 ? g5 : kk) : g6;
                g5 = l5 ? (l4 ? g4b : kk) : g5;
                g4b = l4 ? (l3 ? g3 : kk) : g4b;
                g3 = l3 ? (l2 ? g2 : kk) : g3;
                g2 = l2 ? (l1 ? g1 : kk) : g2;
                g1 = l1 ? (l0 ? g0 : kk) : g1;
                g0 = l0 ? kk : g0;
            }
        }
        int cnt = 0;
        for (int t = 0; t < 33; ++t) {
            unsigned long long best = g0;
            #pragma unroll
            for (int off = 32; off; off >>= 1) {
                unsigned long long o = __shfl_xor(best, off);
                best = o < best ? o : best;
            }
            if (t == 32) {
                d33v = __builtin_bit_cast(float, (unsigned)(best >> 32));
                break;
            }
            int j = (int)(unsigned)best;
            bool won = (lane == ((j >> 2) & 63));
            if (won) sel |= 1u << (((j >> 8) << 2) | (j & 3));
            if (t == 31) d32v = __builtin_bit_cast(float, (unsigned)(best >> 32));

            if (won) cnt++;
            bool needScan = won && (cnt >= 8);
            bool adv = won && (cnt < 8);
            g0 = adv ? g1 : g0;  g1 = adv ? g2 : g1;  g2 = adv ? g3 : g2;
            g3 = adv ? g4b : g3; g4b = adv ? g5 : g4b; g5 = adv ? g6 : g5;
            g6 = adv ? g7 : g6;  g7 = adv ? ~0ull : g7;
            if (__any(needScan)) {
                if (needScan) {
                    float bv = FLT_MAX; int bs = 0; bool found = false;
                    #pragma unroll
                    for (int s = 0; s < 32; ++s) {
                        bool ok = !((sel >> s) & 1u);
                        bool lt = ok && (d[s] < bv);
                        bv = lt ? d[s] : bv; bs = lt ? s : bs; found |= ok;
                    }
                    g0 = found
                       ? (((unsigned long long)__builtin_bit_cast(unsigned, bv) << 32)
                          | (unsigned)((bs >> 2) * 256 + lane * 4 + (bs & 3)))
                       : ~0ull;
                }
            }
        }
    }

    // ---- Phase 3: boundary-gap guard (exact fp32 recompute for the window) ----
    if (d33v - d32v < MARGIN) {
        float lo2 = d32v - MARGIN, hi2 = d33v + MARGIN;
        unsigned cand = 0;
        #pragma unroll
        for (int s = 0; s < 32; ++s)
            if (d[s] >= lo2 && d[s] <= hi2) cand |= 1u << s;

        const unsigned short* qrow = q_s + (long)g * QS;
        const u16x4* qh = (const u16x4*)&qrow[lane * 12];
        const u16x4* ql = (const u16x4*)&qrow[DD + lane * 12];
        #pragma unroll
        for (int s = 0; s < 32; ++s) {
            unsigned long long m = __ballot((cand >> s) & 1u);
            while (m) {
                int l2 = __ffsll(m) - 1;
                m &= m - 1;
                int j = (s >> 2) * 256 + l2 * 4 + (s & 3);
                const unsigned short* krow = k_s + ((long)b * SS + j) * QS;
                const u16x4* kh = (const u16x4*)&krow[lane * 12];
                const u16x4* kl = (const u16x4*)&krow[DD + lane * 12];
                float part = 0.f;
                #pragma unroll
                for (int c = 0; c < 3; ++c) {
                    u16x4 qa = qh[c], qb = ql[c], ka = kh[c], kb2 = kl[c];
                    #pragma unroll
                    for (int e = 0; e < 4; ++e) {
                        float qv = f16f(qa[e]) + f16f(qb[e]) * 0.015625f;
                        float kv = f16f(ka[e]) + f16f(kb2[e]) * 0.015625f;
                        part = fmaf(qv, kv, part);
                    }
                }
                #pragma unroll
                for (int off = 32; off; off >>= 1) part += __shfl_xor(part, off);
                float dd = qn[g] + kn[(long)b * SS + j] - 2.f * part;
                dd = fmaxf(dd, 0.f);
                if (lane == l2) d[s] = dd;
            }
        }

        sel &= ~cand;
        int C = 0;
        #pragma unroll
        for (int s = 0; s < 32; ++s) C += (int)__popcll(__ballot((sel >> s) & 1u));
        int need = KNEI - C;
        for (int t = 0; t < need; ++t) {
            unsigned long long best = ~0ull;
            #pragma unroll
            for (int s = 0; s < 32; ++s) {
                if (((cand >> s) & 1u) && !((sel >> s) & 1u)) {
                    unsigned long long key =
                        ((unsigned long long)__builtin_bit_cast(unsigned, d[s]) << 32)
                        | (unsigned)((s >> 2) * 256 + lane * 4 + (s & 3));
                    best = key < best ? key : best;
                }
            }
            #pragma unroll
            for (int off = 32; off; off >>= 1) {
                unsigned long long o = __shfl_xor(best, off);
                best = o < best ? o : best;
            }
            if (best != ~0ull) {
                int j = (int)(unsigned)best;
                if (lane == ((j >> 2) & 63)) sel |= 1u << (((j >> 8) << 2) | (j & 3));
            }
        }
    }

    // ---- Phase 4: rank-based selected-index assignment + batched bf16 gather ----
    int myj = 0;
    {
        int target = lane & 31;            // lane p (and p+32) own the p-th selected index
        int cum = 0;
        #pragma unroll
        for (int s = 0; s < 32; ++s) {
            unsigned long long m = __ballot((sel >> s) & 1u);
            int c = (int)__popcll(m);
            if (target >= cum && target < cum + c) {
                int nth = target - cum;
                unsigned long long mm = m;
                int base = 0;
                int c32 = (int)__popcll(mm & 0xffffffffull);
                if (nth >= c32) { nth -= c32; mm >>= 32; base += 32; }
                int c16 = (int)__popcll(mm & 0xffffull);
                if (nth >= c16) { nth -= c16; mm >>= 16; base += 16; }
                int c8 = (int)__popcll(mm & 0xffull);
                if (nth >= c8) { nth -= c8; mm >>= 8; base += 8; }
                int c4 = (int)__popcll(mm & 0xfull);
                if (nth >= c4) { nth -= c4; mm >>= 4; base += 4; }
                int c2 = (int)__popcll(mm & 0x3ull);
                if (nth >= c2) { nth -= c2; mm >>= 2; base += 2; }
                int c1 = (int)(mm & 1ull);
                if (nth >= c1) { base += 1; }
                myj = (s >> 2) * 256 + base * 4 + (s & 3);
            }
            cum += c;
        }
    }
    f32x4 a0 = {0.f, 0.f, 0.f, 0.f}, a1 = a0, a2 = a0;
    #pragma unroll
    for (int tb = 0; tb < 8; ++tb) {
        u16x4 r0[4], r1[4], r2[4];
        #pragma unroll
        for (int u = 0; u < 4; ++u) {
            int j = __shfl(myj, tb * 4 + u);
            const u16x4* vr = (const u16x4*)(vb + (long)j * DD);
            r0[u] = vr[lane];
            r1[u] = vr[lane + 64];
            r2[u] = vr[lane + 128];
        }
        #pragma unroll
        for (int u = 0; u < 4; ++u) {
            #pragma unroll
            for (int e = 0; e < 4; ++e) {
                a0[e] += bf16f(r0[u][e]);
                a1[e] += bf16f(r1[u][e]);
                a2[e] += bf16f(r2[u][e]);
            }
        }
    }
    const float sc = 1.0f / 32.0f;
    unsigned short* trow = topo_f16 + (long)g * DD;
    #pragma unroll
    for (int c = 0; c < 3; ++c) {
        f32x4 x = (c == 0) ? a0 : (c == 1) ? a1 : a2;
        u16x4 hi4;
        #pragma unroll
        for (int e = 0; e < 4; ++e) hi4[e] = ff16(x[e] * sc);
        *(u16x4*)&trow[c * 256 + lane * 4] = hi4;
    }
}

extern "C" void kernel_launch(void* const* d_in, const int* in_sizes, int n_in,
                              void* d_out, int out_size, void* d_ws, size_t ws_size,
                              hipStream_t stream)
{
    const float* hs = (const float*)d_in[0];
    const float* Wq = (const float*)d_in[1];
    const float* bq = (const float*)d_in[2];
    const float* Wk = (const float*)d_in[3];
    const float* bk = (const float*)d_in[4];
    const float* Wv = (const float*)d_in[5];
    const float* bv = (const float*)d_in[6];
    const float* W1 = (const float*)d_in[7];
    const float* b1 = (const float*)d_in[8];
    const float* W2 = (const float*)d_in[9];
    const float* b2 = (const float*)d_in[10];
    float* out = (float*)d_out;

    // ---- workspace layout (peak ~180 MB), time-overlaid ----
    char* w = (char*)d_ws;
    const long DISTB = (long)BB * SS * SS * 4;        // 67,108,864
    const long VB    = (long)BSR * DD * 2;            // 12,582,912 (bf16 v)
    const long WSPL  = (long)DD * K2;                 // elems per 3-term split weight

    float*          dist   = (float*)w;                               // [0, 67.1M)
    unsigned short* h_f16  = (unsigned short*)w;                      // overlays dead dist
    unsigned short* v      = (unsigned short*)(w + DISTB);            // bf16 v
    unsigned short* q_s    = (unsigned short*)(w + DISTB + VB);       // 2-slot
    unsigned short* k_s    = q_s + (long)BSR * QS;                    // 2-slot
    unsigned short* hs_s   = k_s + (long)BSR * QS;                    // 3-term A-layout
    unsigned short* topo_f16 = hs_s;                                  // overlays dead hs_s
    unsigned short* Wqkv_s = hs_s + (long)BSR * K2;                   // 3 weight splits adjacent
    char* tail  = (char*)(Wqkv_s + 3 * WSPL);
    float* qn   = (float*)tail;                        // 8192
    float* kn   = qn + BSR;                            // 8192
    float* pn   = kn + BSR;                            // qnp[8192][12] + knp[8192][12]
    float* bqkv = pn + (long)2 * BSR * 12;             // 2304
    unsigned short* W12 = (unsigned short*)(bqkv + 2304);
    unsigned short* W1_f16 = W12;
    unsigned short* W2_f16 = W12 + (long)DD * DD;      // +2.25 MB

    dim3 blk(256);

    // merged prologue: weight splits + hs split + W1/W2 conv + bias concat
    prep<<<4521, blk, 0, stream>>>(Wq, Wk, Wv, hs, W1, W2, bq, bk, bv,
                                   Wqkv_s, hs_s, W1_f16, W2_f16, bqkv);

    // fused QKV gemm: q -> 2-slot q_s + norms, k -> 2-slot k_s + norms, v -> bf16 (K=768)
    gemm_mfma<4><<<dim3(2304 / 128, BSR / 128, 1), blk, 0, stream>>>(
        hs_s, Wqkv_s, bqkv, nullptr, BSR, 2304, K2, K2, K2,
        q_s, k_s, v, pn);

    finish_norms<<<(2 * BSR) / 256, blk, 0, stream>>>(pn, qn, kn);

    // squared distance matrix per batch: single-term f16 (Kd=768, stride QS)
    gemm256_dist<<<dim3(SS / 256, SS / 256, BB), dim3(512), 0, stream>>>(
        q_s, k_s, qn, kn, dist, SS, DD, QS, QS,
        (long)SS * QS, (long)SS * QS, (long)SS * SS, SS);

    select_mean<<<BSR / 4, blk, 0, stream>>>(dist, v, q_s, k_s, qn, kn, topo_f16);

    // MLP single-term f16: gemm1 -> compact f16 h (relu fused), gemm2 -> f32 out
    gemm_mfma<3><<<dim3(DD / 128, BSR / 128, 1), blk, 0, stream>>>(
        topo_f16, W1_f16, b1, nullptr, BSR, DD, DD, DD, DD,
        h_f16, nullptr, nullptr, nullptr);
    gemm_mfma<0><<<dim3(DD / 128, BSR / 128, 1), blk, 0, stream>>>(
        h_f16, W2_f16, b2, out, BSR, DD, DD, DD, DD,
        nullptr, nullptr, nullptr, nullptr);
}